// Round 1
// baseline (81.642 us; speedup 1.0000x reference)
//
#include <hip/hip_runtime.h>

// Problem constants (match reference)
#define CIN_  128
#define H_    28
#define W_    28
#define COUT_ 32
#define B_    512
// GEMM view per (b,h): Y[32 x 28] = Wm[32 x 384] * Xwin[384 x 28]
// K order: kappa = tap*128 + channel, chunked in 12 chunks of 32.

typedef __attribute__((ext_vector_type(8))) short short8;  // 8 bf16 in 4 VGPRs
typedef __attribute__((ext_vector_type(4))) float f32x4;

__device__ __forceinline__ short f2bf(float f) {
    union { float f; unsigned u; } v; v.f = f;
    unsigned u = v.u + 0x7fffu + ((v.u >> 16) & 1u);   // RNE to bf16
    return (short)(u >> 16);
}

// ---------------------------------------------------------------------------
// Pre-pass: build bf16 A-fragments of Wm in d_ws.
// Fragment f = mt*12 + kc  (mt: 0..1 M-tile of 16 couts, kc: 0..11 K-chunk of 32)
// Element (lane l, slot j): Wm[jo = mt*16 + (l&15)][i = (kc&3)*32 + (l>>4)*8 + j][tap = kc>>2]
// Stored flat: ws[f*512 + l*8 + j]  -> lane l loads 16B at f*1024 + l*16 bytes.
// ---------------------------------------------------------------------------
__global__ void prep_w_kernel(const float* __restrict__ w, short* __restrict__ wsA) {
    int t = blockIdx.x * 256 + threadIdx.x;      // 24*512 = 12288 threads
    int frag = t >> 9;
    int rem  = t & 511;
    int l = rem >> 3;
    int j = rem & 7;
    int mt = frag / 12;
    int kc = frag % 12;
    int tap = kc >> 2;
    int i  = (kc & 3) * 32 + (l >> 4) * 8 + j;
    int jo = mt * 16 + (l & 15);
    wsA[t] = f2bf(w[(jo * CIN_ + i) * 3 + tap]);
}

// ---------------------------------------------------------------------------
// Main kernel: one block per batch b, 4 waves, each wave does 7 h-rows.
// LDS per wave: x-row transposed [w_tilde 0..33][128 ch] bf16, XOR-swizzled:
//   element (wt, i) at short index  wt*128 + (((i>>3) ^ (wt&15))<<3 | (i&7))
// wt = w + tap  (w_real = wt - 1); rows 0 and 29..33 are zeros (padding).
// ---------------------------------------------------------------------------
template<bool USE_WS>
__global__ __launch_bounds__(256)
void conv_kernel(const float* __restrict__ x, const float* __restrict__ w,
                 const short* __restrict__ wsA, float* __restrict__ out) {
    __shared__ short lds[4 * 34 * CIN_];         // 34816 B
    const int tid = threadIdx.x;
    const int wv  = tid >> 6;
    const int l   = tid & 63;
    const int b   = blockIdx.x;
    short* wbuf = &lds[wv * 34 * CIN_];

    // ---- A fragments in registers (24 x 8 bf16 = 96 VGPR) ----
    short8 afrag[24];
    if (USE_WS) {
#pragma unroll
        for (int f = 0; f < 24; ++f)
            afrag[f] = *reinterpret_cast<const short8*>(wsA + f * 512 + l * 8);
    } else {
#pragma unroll
        for (int mt = 0; mt < 2; ++mt)
#pragma unroll
            for (int kc = 0; kc < 12; ++kc) {
                int tap = kc >> 2;
                int ib  = (kc & 3) * 32 + (l >> 4) * 8;
                int jo  = mt * 16 + (l & 15);
                short8 a;
#pragma unroll
                for (int j = 0; j < 8; ++j)
                    a[j] = f2bf(w[(jo * CIN_ + ib + j) * 3 + tap]);
                afrag[mt * 12 + kc] = a;
            }
    }

    // ---- zero the pad rows (wt = 0, 29..33) once; staging never touches them
    {
        short8 z;
#pragma unroll
        for (int q = 0; q < 8; ++q) z[q] = 0;
        for (int idx = l; idx < 96; idx += 64) {       // 6 rows * 16 chunks
            int rr  = idx >> 4;                        // 0..5
            int row = (rr == 0) ? 0 : (28 + rr);       // 0,29,30,31,32,33
            int c   = idx & 15;
            *reinterpret_cast<short8*>(&wbuf[row * CIN_ + c * 8]) = z;
        }
    }

    const float* xb = x + (size_t)b * CIN_ * H_ * W_;
    float*       ob = out + (size_t)b * COUT_ * H_ * W_;

    for (int r = 0; r < 7; ++r) {
        const int h = wv * 7 + r;

        // ---- stage x[b,:,h,:] -> LDS transposed bf16, swizzled ----
        // 128 ch * 7 float4 = 896 float4 loads, 14 per lane, coalesced.
#pragma unroll
        for (int it = 0; it < 14; ++it) {
            int f4 = it * 64 + l;            // 0..895
            int i  = f4 / 7;
            int w4 = f4 % 7;
            f32x4 v = *reinterpret_cast<const f32x4*>(xb + i * (H_ * W_) + h * W_ + w4 * 4);
#pragma unroll
            for (int e = 0; e < 4; ++e) {
                int wt   = w4 * 4 + e + 1;   // 1..28
                int sidx = wt * CIN_ + ((((i >> 3) ^ (wt & 15)) << 3) | (i & 7));
                wbuf[sidx] = f2bf(v[e]);
            }
        }
        __syncthreads();

        // ---- GEMM: 2 M-tiles x 2 N-tiles x 12 K-chunks of 32 ----
        f32x4 acc[2][2];
#pragma unroll
        for (int mt = 0; mt < 2; ++mt)
#pragma unroll
            for (int nt = 0; nt < 2; ++nt)
#pragma unroll
                for (int q = 0; q < 4; ++q) acc[mt][nt][q] = 0.0f;

#pragma unroll
        for (int kc = 0; kc < 12; ++kc) {
            const int tap = kc >> 2;
            const int c   = (kc & 3) * 4 + (l >> 4);   // chunk index of lane's 8 channels
#pragma unroll
            for (int nt = 0; nt < 2; ++nt) {
                int wt = nt * 16 + (l & 15) + tap;     // 0..33
                const short8 bfrag = *reinterpret_cast<const short8*>(
                    &wbuf[wt * CIN_ + ((c ^ (wt & 15)) << 3)]);
                acc[0][nt] = __builtin_amdgcn_mfma_f32_16x16x32_bf16(
                    afrag[kc],      bfrag, acc[0][nt], 0, 0, 0);
                acc[1][nt] = __builtin_amdgcn_mfma_f32_16x16x32_bf16(
                    afrag[12 + kc], bfrag, acc[1][nt], 0, 0, 0);
            }
        }

        // ---- store with roll: y row h -> out row (h+1)%28 ----
        const int ho = (h + 1 == H_) ? 0 : (h + 1);
#pragma unroll
        for (int mt = 0; mt < 2; ++mt)
#pragma unroll
            for (int nt = 0; nt < 2; ++nt)
#pragma unroll
                for (int rr = 0; rr < 4; ++rr) {
                    int j    = mt * 16 + (l >> 4) * 4 + rr;
                    int wcol = nt * 16 + (l & 15);
                    if (wcol < W_)
                        ob[(j * H_ + ho) * W_ + wcol] = acc[mt][nt][rr];
                }
        __syncthreads();   // before next row overwrites the wave's LDS buffer
    }
}

extern "C" void kernel_launch(void* const* d_in, const int* in_sizes, int n_in,
                              void* d_out, int out_size, void* d_ws, size_t ws_size,
                              hipStream_t stream) {
    (void)in_sizes; (void)n_in; (void)out_size;
    const float* x = (const float*)d_in[0];
    const float* w = (const float*)d_in[1];
    float* out = (float*)d_out;

    if (ws_size >= (size_t)(24 * 512 * sizeof(short))) {
        short* wsA = (short*)d_ws;
        prep_w_kernel<<<dim3(48), dim3(256), 0, stream>>>(w, wsA);
        conv_kernel<true><<<dim3(B_), dim3(256), 0, stream>>>(x, w, wsA, out);
    } else {
        conv_kernel<false><<<dim3(B_), dim3(256), 0, stream>>>(x, w, (const short*)nullptr, out);
    }
}

// Round 2
// 69.880 us; speedup vs baseline: 1.1683x; 1.1683x over previous
//
#include <hip/hip_runtime.h>

// Problem constants (match reference)
#define CIN_  128
#define H_    28
#define W_    28
#define COUT_ 32
#define B_    512
// GEMM view per (b,h): Y[32 x 28] = Wm[32 x 384] * Xwin[384 x 28]
// K order: kappa = tap*128 + channel, chunked in 12 chunks of 32.

typedef __attribute__((ext_vector_type(8))) short short8;  // 8 bf16 in 4 VGPRs
typedef __attribute__((ext_vector_type(4))) float f32x4;

__device__ __forceinline__ short f2bf(float f) {
    union { float f; unsigned u; } v; v.f = f;
    unsigned u = v.u + 0x7fffu + ((v.u >> 16) & 1u);   // RNE to bf16
    return (short)(u >> 16);
}

// ---------------------------------------------------------------------------
// Pre-pass: build bf16 A-fragments of Wm in d_ws.
// Fragment f = mt*12 + kc  (mt: 0..1 M-tile of 16 couts, kc: 0..11 K-chunk of 32)
// Element (lane l, slot j): Wm[jo = mt*16 + (l&15)][i = (kc&3)*32 + (l>>4)*8 + j][tap = kc>>2]
// Stored flat: ws[f*512 + l*8 + j]  -> lane l loads 16B at f*1024 + l*16 bytes.
// ---------------------------------------------------------------------------
__global__ void prep_w_kernel(const float* __restrict__ w, short* __restrict__ wsA) {
    int t = blockIdx.x * 256 + threadIdx.x;      // 24*512 = 12288 threads
    int frag = t >> 9;
    int rem  = t & 511;
    int l = rem >> 3;
    int j = rem & 7;
    int mt = frag / 12;
    int kc = frag % 12;
    int tap = kc >> 2;
    int i  = (kc & 3) * 32 + (l >> 4) * 8 + j;
    int jo = mt * 16 + (l & 15);
    wsA[t] = f2bf(w[(jo * CIN_ + i) * 3 + tap]);
}

// ---------------------------------------------------------------------------
// Main kernel v2: grid (14, 512), block 128 (2 waves). Wave wv computes one
// h-row: h = blockIdx.x*2 + wv. Block-cooperative staging of both rows
// (consecutive h -> 448B contiguous global segments), one barrier, then
// per-wave GEMM from its own LDS buffer.
// LDS per wave: x-row transposed [wt 0..33][128 ch] bf16, XOR-swizzled:
//   (wt, i) at short index  wt*128 + (((i>>3) ^ (wt&15))<<3 | (i&7))
// wt = w + tap (w_real = wt-1). Rows 0 and 29 zeroed (padding); rows 30..33
// are never written: they only feed output cols wcol>=28, which are discarded
// (MFMA columns are independent), so stale LDS there is harmless.
// ---------------------------------------------------------------------------
template<bool USE_WS>
__global__ __launch_bounds__(128, 5)
void conv_kernel(const float* __restrict__ x, const float* __restrict__ w,
                 const short* __restrict__ wsA, float* __restrict__ out) {
    __shared__ short lds[2][34 * CIN_];          // 2 x 8704 B = 17408 B
    const int tid = threadIdx.x;
    const int wv  = tid >> 6;
    const int l   = tid & 63;
    const int hg  = blockIdx.x;                  // 0..13
    const int b   = blockIdx.y;                  // 0..511
    const int h0  = hg * 2;

    const float* xb = x + (size_t)b * (CIN_ * H_ * W_);

    // ---- zero pad rows wt=0 and wt=29 in both wave buffers ----
    // 2 buf * 2 rows * 128 shorts = 512 shorts; 4 shorts (8B) per thread.
    {
        int e   = tid * 4;                       // 0..508
        int buf = e >> 8;                        // 0..1
        int row = ((e >> 7) & 1) ? 29 : 0;
        int c   = e & 127;
        *reinterpret_cast<ulong1*>(&lds[buf][row * CIN_ + c]) = ulong1{0};
    }

    // ---- block-cooperative staging: 2 rows, 128 ch, 7 f32x4 each ----
    // f4 = t*128 + tid; i = ch, hl = local row, w4 = quad index.
#pragma unroll
    for (int t = 0; t < 14; ++t) {
        int f4  = t * 128 + tid;                 // 0..1791
        int i   = f4 / 14;
        int rem = f4 % 14;
        int hl  = rem / 7;
        int w4  = rem % 7;
        f32x4 v = *reinterpret_cast<const f32x4*>(xb + i * (H_ * W_) + (h0 + hl) * W_ + w4 * 4);
        short* buf = lds[hl];
#pragma unroll
        for (int e = 0; e < 4; ++e) {
            int wt   = w4 * 4 + e + 1;           // 1..28
            int sidx = wt * CIN_ + ((((i >> 3) ^ (wt & 15)) << 3) | (i & 7));
            buf[sidx] = f2bf(v[e]);
        }
    }
    __syncthreads();

    // ---- per-wave GEMM: 2 M-tiles x 2 N-tiles, K split in two halves ----
    short* wbuf = lds[wv];
    const int h = h0 + wv;

    f32x4 acc[2][2];
#pragma unroll
    for (int mt = 0; mt < 2; ++mt)
#pragma unroll
        for (int nt = 0; nt < 2; ++nt)
#pragma unroll
            for (int q = 0; q < 4; ++q) acc[mt][nt][q] = 0.0f;

#pragma unroll
    for (int half = 0; half < 2; ++half) {
        short8 a0[6], a1[6];                     // 12 frags live = 48 VGPR
        if (USE_WS) {
#pragma unroll
            for (int k6 = 0; k6 < 6; ++k6) {
                int kc = half * 6 + k6;
                a0[k6] = *reinterpret_cast<const short8*>(wsA + kc * 512 + l * 8);
                a1[k6] = *reinterpret_cast<const short8*>(wsA + (12 + kc) * 512 + l * 8);
            }
        } else {
#pragma unroll
            for (int k6 = 0; k6 < 6; ++k6) {
                int kc  = half * 6 + k6;
                int tap = kc >> 2;
                int ib  = (kc & 3) * 32 + (l >> 4) * 8;
#pragma unroll
                for (int j = 0; j < 8; ++j) {
                    a0[k6][j] = f2bf(w[((l & 15) * CIN_ + ib + j) * 3 + tap]);
                    a1[k6][j] = f2bf(w[((16 + (l & 15)) * CIN_ + ib + j) * 3 + tap]);
                }
            }
        }
#pragma unroll
        for (int k6 = 0; k6 < 6; ++k6) {
            int kc  = half * 6 + k6;
            int tap = kc >> 2;
            int c   = (kc & 3) * 4 + (l >> 4);   // chunk index of lane's 8 channels
#pragma unroll
            for (int nt = 0; nt < 2; ++nt) {
                int wt = nt * 16 + (l & 15) + tap;   // 0..33
                const short8 bfrag = *reinterpret_cast<const short8*>(
                    &wbuf[wt * CIN_ + ((c ^ (wt & 15)) << 3)]);
                acc[0][nt] = __builtin_amdgcn_mfma_f32_16x16x32_bf16(
                    a0[k6], bfrag, acc[0][nt], 0, 0, 0);
                acc[1][nt] = __builtin_amdgcn_mfma_f32_16x16x32_bf16(
                    a1[k6], bfrag, acc[1][nt], 0, 0, 0);
            }
        }
    }

    // ---- store with roll: y row h -> out row (h+1)%28 ----
    float* ob = out + (size_t)b * (COUT_ * H_ * W_);
    const int ho = (h + 1 == H_) ? 0 : (h + 1);
#pragma unroll
    for (int mt = 0; mt < 2; ++mt)
#pragma unroll
        for (int nt = 0; nt < 2; ++nt)
#pragma unroll
            for (int rr = 0; rr < 4; ++rr) {
                int j    = mt * 16 + (l >> 4) * 4 + rr;
                int wcol = nt * 16 + (l & 15);
                if (wcol < W_)
                    ob[(j * H_ + ho) * W_ + wcol] = acc[mt][nt][rr];
            }
}

extern "C" void kernel_launch(void* const* d_in, const int* in_sizes, int n_in,
                              void* d_out, int out_size, void* d_ws, size_t ws_size,
                              hipStream_t stream) {
    (void)in_sizes; (void)n_in; (void)out_size;
    const float* x = (const float*)d_in[0];
    const float* w = (const float*)d_in[1];
    float* out = (float*)d_out;

    if (ws_size >= (size_t)(24 * 512 * sizeof(short))) {
        short* wsA = (short*)d_ws;
        prep_w_kernel<<<dim3(48), dim3(256), 0, stream>>>(w, wsA);
        conv_kernel<true><<<dim3(14, 512), dim3(128), 0, stream>>>(x, w, wsA, out);
    } else {
        conv_kernel<false><<<dim3(14, 512), dim3(128), 0, stream>>>(x, w, (const short*)nullptr, out);
    }
}